// Round 7
// baseline (3014.538 us; speedup 1.0000x reference)
//
#include <hip/hip_runtime.h>

typedef _Float16 h8 __attribute__((ext_vector_type(8)));
typedef _Float16 h2 __attribute__((ext_vector_type(2)));
typedef float f4 __attribute__((ext_vector_type(4)));

#define N_NODES 100000
#define NPAD    100096   // 1564*64
#define N_EDGES 1600000
#define T_P  18
#define U    256
#define KP   288         // padded K: 8 AXt + 256 H + 24 zero
#define LDW  296         // LDS row stride in halfs (148 words = 20 mod 32 -> 2-way alias only, free)
#define NB_SCAN 391      // ceil(N_NODES/256)

#define LOG2E  1.44269504f
#define LOG2E2 2.88539008f

// ---------------- degree / norm / CSR ----------------
__global__ void k_init_deg(float* deg){
    int i = blockIdx.x*256 + threadIdx.x;
    if (i < N_NODES) deg[i] = 1.0f;
}
__global__ void k_deg(const int* __restrict__ ei, const float* __restrict__ w, float* deg){
    int e = blockIdx.x*256 + threadIdx.x;
    if (e < N_EDGES) atomicAdd(&deg[ei[N_EDGES + e]], w[e]);
}
__global__ void k_dinv(const float* deg, float* dinv){
    int i = blockIdx.x*256 + threadIdx.x;
    if (i < N_NODES) dinv[i] = rsqrtf(deg[i]);
}
__global__ void k_count(const int* __restrict__ ei, int* cnt){
    int e = blockIdx.x*256 + threadIdx.x;
    if (e < N_EDGES) atomicAdd(&cnt[ei[N_EDGES + e]], 1);
}
// parallel scan: per-256-chunk sums -> scan of partials -> emit offsets
__global__ void k_partial(const int* __restrict__ cnt, int* part){
    __shared__ int red[256];
    int b = blockIdx.x, i = b*256 + threadIdx.x;
    red[threadIdx.x] = (i < N_NODES) ? cnt[i] : 0;
    __syncthreads();
    for (int d = 128; d > 0; d >>= 1){
        if (threadIdx.x < d) red[threadIdx.x] += red[threadIdx.x + d];
        __syncthreads();
    }
    if (threadIdx.x == 0) part[b] = red[0];
}
__global__ void k_scan_part(const int* __restrict__ part, int* pbase){
    __shared__ int s[512];
    int tid = threadIdx.x;
    int v = (tid < NB_SCAN) ? part[tid] : 0;
    s[tid] = v; __syncthreads();
    for (int d = 1; d < 512; d <<= 1){
        int t2 = (tid >= d) ? s[tid - d] : 0;
        __syncthreads();
        s[tid] += t2;
        __syncthreads();
    }
    if (tid < NB_SCAN) pbase[tid] = s[tid] - v;   // exclusive
}
__global__ void k_emit(const int* __restrict__ cnt, const int* __restrict__ pbase,
                       int* rowp, int* ccur){
    __shared__ int s[256];
    int b = blockIdx.x, tid = threadIdx.x, i = b*256 + tid;
    int v = (i < N_NODES) ? cnt[i] : 0;
    s[tid] = v; __syncthreads();
    for (int d = 1; d < 256; d <<= 1){
        int t2 = (tid >= d) ? s[tid - d] : 0;
        __syncthreads();
        s[tid] += t2;
        __syncthreads();
    }
    int excl = s[tid] - v + pbase[b];
    if (i < N_NODES){
        rowp[i] = excl; ccur[i] = excl;
        if (i == N_NODES - 1) rowp[N_NODES] = excl + v;
    }
}
__global__ void k_scatter(const int* __restrict__ ei, const float* __restrict__ w,
                          const float* __restrict__ dinv, int* ccur,
                          int* __restrict__ csrc, float* __restrict__ cnrm){
    int e = blockIdx.x*256 + threadIdx.x;
    if (e >= N_EDGES) return;
    int s = ei[e], d = ei[N_EDGES + e];
    int pos = atomicAdd(&ccur[d], 1);
    csrc[pos] = s;
    cnrm[pos] = dinv[s] * w[e] * dinv[d];
}
// one thread per (node, feature): 18 time-accumulators, fp16 out
__global__ void k_gather_nf(const float* __restrict__ x, const float* __restrict__ dinv,
                            const int* __restrict__ rowp, const int* __restrict__ csrc,
                            const float* __restrict__ cnrm, _Float16* __restrict__ AXh){
    int idx = blockIdx.x*256 + threadIdx.x;
    if (idx >= N_NODES*8) return;
    int n = idx >> 3, f = idx & 7;
    float dv = dinv[n];
    float w0 = dv * dv;
    const float* xb = x + (size_t)n*144 + f*18;
    float s[T_P];
    #pragma unroll
    for (int t = 0; t < T_P; t++) s[t] = w0 * xb[t];
    int p1 = rowp[n+1];
    for (int p = rowp[n]; p < p1; p++){
        float w = cnrm[p];
        const float* xs = x + (size_t)csrc[p]*144 + f*18;
        #pragma unroll
        for (int t = 0; t < T_P; t++) s[t] += w * xs[t];
    }
    #pragma unroll
    for (int t = 0; t < T_P; t++)
        AXh[((size_t)t*NPAD + n)*8 + f] = (_Float16)s[t];
}

// ---------------- weight prep ----------------
__global__ void k_probs(const float* att, float* probs){
    if (threadIdx.x == 0 && blockIdx.x == 0){
        float mx = -1e30f;
        for (int t = 0; t < T_P; t++) mx = fmaxf(mx, att[t]);
        float e[T_P], s = 0.f;
        for (int t = 0; t < T_P; t++){ e[t] = __expf(att[t] - mx); s += e[t]; }
        for (int t = 0; t < T_P; t++) probs[t] = e[t] / s;
    }
}
__global__ void k_wprime(const float* Wz, const float* bz, const float* Wlz, const float* blz,
                         const float* Wr, const float* br, const float* Wlr, const float* blr,
                         const float* Wh, const float* bh, const float* Wlh, const float* blh,
                         float* wprime, float* biasg){
    int idx = blockIdx.x*256 + threadIdx.x;
    if (idx >= 3*9*256) return;
    int g = idx / (9*256); int rem = idx - g*9*256;
    int row = rem / 256;   int u = rem - row*256;
    const float* W  = g==0 ? Wz  : (g==1 ? Wr  : Wh);
    const float* Wl = g==0 ? Wlz : (g==1 ? Wlr : Wlh);
    const float* bb = g==0 ? bz  : (g==1 ? br  : bh);
    const float* bl = g==0 ? blz : (g==1 ? blr : blh);
    float s = 0.f;
    if (row < 8){
        for (int c = 0; c < U; c++) s += W[row*U + c] * Wl[c*U + u];
        wprime[(g*8 + row)*U + u] = s;
    } else {
        for (int c = 0; c < U; c++) s += bb[c] * Wl[c*U + u];
        biasg[g*U + u] = s + bl[u];
    }
}
// B1t [512][288] (Z|R), B2t [256][288] (H~), n-major fp16, K-padded with 0
__global__ void k_fill_gates(const float* __restrict__ wprime, const float* __restrict__ Wlz,
                             const float* __restrict__ Wlr, const float* __restrict__ Wlh,
                             _Float16* __restrict__ B1t, _Float16* __restrict__ B2t){
    int idx = blockIdx.x*256 + threadIdx.x;
    if (idx >= 768*KP) return;
    int n = idx / KP, k = idx - n*KP;
    int g = (n < 256) ? 0 : ((n < 512) ? 1 : 2);
    int u = n & 255;
    const float* Wl = g==0 ? Wlz : (g==1 ? Wlr : Wlh);
    float v;
    if (k < 8)        v = wprime[(g*8 + k)*U + u];
    else if (k < 264) v = Wl[(256 + (k - 8))*U + u];
    else              v = 0.f;
    if (n < 512) B1t[(size_t)n*KP + k] = (_Float16)v;
    else         B2t[(size_t)(n - 512)*KP + k] = (_Float16)v;
}
// MLP weights in same padded layout: rows k<8 and k>=264 are zero, k in [8,264) = W[k-8][n]
__global__ void k_fill_mlp(const float* __restrict__ W1, const float* __restrict__ W2,
                           const float* __restrict__ W3, const float* __restrict__ Wo,
                           _Float16* W1t, _Float16* W2t, _Float16* W3t, _Float16* WoT){
    int idx = blockIdx.x*256 + threadIdx.x;
    if (idx >= 3*U*KP + 64*KP) return;
    if (idx < 3*U*KP){
        int l = idx / (U*KP); int rem = idx - l*U*KP;
        int n = rem / KP, k = rem - n*KP;
        const float* W = l==0 ? W1 : (l==1 ? W2 : W3);
        _Float16*   Wt = l==0 ? W1t : (l==1 ? W2t : W3t);
        Wt[(size_t)n*KP + k] = (k >= 8 && k < 264) ? (_Float16)W[(size_t)(k-8)*U + n] : (_Float16)0.f;
    } else {
        int rem = idx - 3*U*KP;
        int n = rem / KP, k = rem - n*KP;
        WoT[(size_t)n*KP + k] = (n < T_P && k >= 8 && k < 264) ? (_Float16)Wo[(size_t)(k-8)*T_P + n] : (_Float16)0.f;
    }
}

// ---------------- fused recurrence + MLP ----------------
// single-B pass: wave tile = 64 rows x 32 cols, g[8] (4 row-frags x 2 col-frags)
__device__ __forceinline__ void gemm_pass(const _Float16* sbuf, const _Float16* __restrict__ Bg,
                                          int brow, int lr, int lq, f4* g){
    for (int kt = 0; kt < 9; kt++){
        h8 af[4], bf[2];
        #pragma unroll
        for (int i = 0; i < 4; i++)
            af[i] = *(const h8*)(sbuf + (i*16 + lr)*LDW + kt*32 + lq*8);
        #pragma unroll
        for (int j = 0; j < 2; j++)
            bf[j] = *(const h8*)(Bg + (size_t)(brow + j*16 + lr)*KP + kt*32 + lq*8);
        #pragma unroll
        for (int i = 0; i < 4; i++)
            #pragma unroll
            for (int j = 0; j < 2; j++)
                g[i*2 + j] = __builtin_amdgcn_mfma_f32_16x16x32_f16(af[i], bf[j], g[i*2 + j], 0, 0, 0);
    }
}
// dual-B pass: reads the A fragments ONCE, feeds two B row-sets (Z and R).
__device__ __forceinline__ void gemm_pass2(const _Float16* sbuf, const _Float16* __restrict__ Bg,
                                           int browZ, int browR, int lr, int lq, f4* gz, f4* gr){
    for (int kt = 0; kt < 9; kt++){
        h8 af[4], bz_[2], br_[2];
        #pragma unroll
        for (int i = 0; i < 4; i++)
            af[i] = *(const h8*)(sbuf + (i*16 + lr)*LDW + kt*32 + lq*8);
        #pragma unroll
        for (int j = 0; j < 2; j++){
            bz_[j] = *(const h8*)(Bg + (size_t)(browZ + j*16 + lr)*KP + kt*32 + lq*8);
            br_[j] = *(const h8*)(Bg + (size_t)(browR + j*16 + lr)*KP + kt*32 + lq*8);
        }
        #pragma unroll
        for (int i = 0; i < 4; i++)
            #pragma unroll
            for (int j = 0; j < 2; j++){
                gz[i*2 + j] = __builtin_amdgcn_mfma_f32_16x16x32_f16(af[i], bz_[j], gz[i*2 + j], 0, 0, 0);
                gr[i*2 + j] = __builtin_amdgcn_mfma_f32_16x16x32_f16(af[i], br_[j], gr[i*2 + j], 0, 0, 0);
            }
    }
}

// epi after the dual Z/R GEMM: z = sigmoid(gz+bz) (kept fp16 in regs),
// hrr = h * sigmoid(gr+br) (staged for the LDS write next slot).
__device__ __forceinline__ void epi_zr(const f4 (&gz)[8], const f4 (&gr)[8],
                                       const h2 (&hr)[16], h2 (&z)[16], h2 (&hrr)[16],
                                       const float (&bzr)[2], const float (&brr)[2]){
    #pragma unroll
    for (int i = 0; i < 4; i++)
        #pragma unroll
        for (int j = 0; j < 2; j++)
            #pragma unroll
            for (int r = 0; r < 4; r++){
                int v = (i*2 + j)*4 + r;
                float zf = __builtin_amdgcn_rcpf(
                    1.f + __builtin_amdgcn_exp2f(fmaf(gz[i*2 + j][r], -LOG2E, bzr[j])));
                float rf = __builtin_amdgcn_rcpf(
                    1.f + __builtin_amdgcn_exp2f(fmaf(gr[i*2 + j][r], -LOG2E, brr[j])));
                z[v>>1][v&1]   = (_Float16)zf;
                hrr[v>>1][v&1] = (_Float16)((float)hr[v>>1][v&1] * rf);
            }
}
// epi after the H~ GEMM: full in-register GRU update (hr <- hn, acc += pt*hn)
__device__ __forceinline__ void epi_upd(const f4 (&g)[8], const h2 (&z)[16],
                                        h2 (&hr)[16], h2 (&acc)[16],
                                        const float (&bhr)[2], float pt){
    #pragma unroll
    for (int i = 0; i < 4; i++)
        #pragma unroll
        for (int j = 0; j < 2; j++)
            #pragma unroll
            for (int r = 0; r < 4; r++){
                int v = (i*2 + j)*4 + r;
                float e2 = __builtin_amdgcn_exp2f(fmaf(g[i*2 + j][r], LOG2E2, bhr[j]));
                float ht = fmaf(-2.f, __builtin_amdgcn_rcpf(e2 + 1.f), 1.f);
                float zf = (float)z[v>>1][v&1];
                float h  = (float)hr[v>>1][v&1];
                float hn = fmaf(zf, h - ht, ht);
                acc[v>>1][v&1] = (_Float16)fmaf(pt, hn, (float)acc[v>>1][v&1]);
                hr[v>>1][v&1]  = (_Float16)hn;
            }
}
__device__ __forceinline__ void write_h16(_Float16* s, const h2 (&val)[16],
                                          int lq, int lr, int wc){
    #pragma unroll
    for (int i = 0; i < 4; i++)
        #pragma unroll
        for (int j = 0; j < 2; j++)
            #pragma unroll
            for (int r = 0; r < 4; r++){
                int v = (i*2 + j)*4 + r;
                s[(i*16 + lq*4 + r)*LDW + 8 + wc + j*16 + lr] = val[v>>1][v&1];
            }
}
__device__ __forceinline__ void write_relu16(_Float16* s, const h2 (&a)[16],
                                             int lq, int lr, int wc){
    #pragma unroll
    for (int i = 0; i < 4; i++)
        #pragma unroll
        for (int j = 0; j < 2; j++)
            #pragma unroll
            for (int r = 0; r < 4; r++){
                int v = (i*2 + j)*4 + r;
                s[(i*16 + lq*4 + r)*LDW + 8 + wc + j*16 + lr] =
                    (_Float16)fmaxf((float)a[v>>1][v&1], 0.f);
            }
}
__device__ __forceinline__ void write_relu_g(_Float16* s, const f4 (&g)[8],
                                             const float (&blv)[2], int lq, int lr, int wc){
    #pragma unroll
    for (int i = 0; i < 4; i++)
        #pragma unroll
        for (int j = 0; j < 2; j++)
            #pragma unroll
            for (int r = 0; r < 4; r++)
                s[(i*16 + lq*4 + r)*LDW + 8 + wc + j*16 + lr] =
                    (_Float16)fmaxf(g[i*2 + j][r] + blv[j], 0.f);
}
__device__ __forceinline__ void head_out(const _Float16* s, const _Float16* __restrict__ WoT,
                                         const float* __restrict__ bo, float* __restrict__ dout,
                                         int rowbase, int lr, int lq){
    const f4 fz = {0.f, 0.f, 0.f, 0.f};
    f4 g[8];
    #pragma unroll
    for (int k = 0; k < 8; k++) g[k] = fz;
    gemm_pass(s, WoT, 0, lr, lq, g);
    #pragma unroll
    for (int i = 0; i < 4; i++)
        #pragma unroll
        for (int j = 0; j < 2; j++)
            #pragma unroll
            for (int r = 0; r < 4; r++){
                int row = i*16 + lq*4 + r;
                int col = j*16 + lr;
                int gm = rowbase + row;
                if (col < T_P && gm < N_NODES)
                    dout[(size_t)gm*T_P + col] = g[i*2 + j][r] + bo[col];
            }
}

// R1: exp2/rcp epilogues, H in regs, AX reg-prefetch -> 1804us. R2/R3/R5: occupancy
//   levers DEAD (unified VGPR+AGPR file: 2 waves/SIMD structural; forcing more
//   spills). R4: dual Z+R pass (-31% LDS traffic) -> 2025us: traffic wasn't the
//   binder; ~70% of cycles are barrier-lockstep stall (MfmaUtil 18 / VALUBusy 23).
// R6 (this design, resubmitted after an infra-level container failure; hazard/OOB/
//   barrier audit clean): TWO independent 64-row strips (X,Y) per workgroup, phase-
//   interleaved (T15 compute||finish across strips). One LDS buffer per strip
//   (in-place H -> H*R -> H' reuse; each overwrite's prior readers drained by the
//   slot barrier), LDS unchanged at 75776B. Every slot pairs one strip's GEMM with
//   the other strip's epilogue VALU + LDS writes, filling MFMA-wait cycles with
//   independent work. B-matrix L2 traffic halves (amortized over 128 rows).
__global__ __attribute__((amdgpu_waves_per_eu(2, 2))) __launch_bounds__(512)
void k_fused(const _Float16* __restrict__ AXh,
             const _Float16* __restrict__ B1t, const _Float16* __restrict__ B2t,
             const float* __restrict__ biasg,
             const _Float16* __restrict__ W1t, const _Float16* __restrict__ W2t,
             const _Float16* __restrict__ W3t, const _Float16* __restrict__ WoT,
             const float* __restrict__ b1, const float* __restrict__ b2,
             const float* __restrict__ b3, const float* __restrict__ bo,
             const float* __restrict__ probs, float* __restrict__ dout){
    __shared__ __align__(16) _Float16 sX[64*LDW];   // strip X: [AXt | H/H*R/H' | pad]
    __shared__ __align__(16) _Float16 sY[64*LDW];   // strip Y: same, half-phase behind
    const int tid  = threadIdx.x;
    const int wave = tid >> 6, lane = tid & 63;
    const int lr = lane & 15, lq = lane >> 4;
    const int wc = wave * 32;                        // this wave's 32 output cols
    const int n0 = blockIdx.x * 128;                 // X rows n0.., Y rows n0+64..

    {   // zero both buffers (H cols start 0, pad cols stay 0)
        uint* w0 = (uint*)sX; uint* w1 = (uint*)sY;
        for (int i = tid; i < 64*LDW/2; i += 512){ w0[i] = 0u; w1[i] = 0u; }
    }
    __syncthreads();
    if (tid < 64)
        *(uint4*)(&sX[tid*LDW]) = *(const uint4*)(AXh + ((size_t)0*NPAD + n0 + tid)*8);
    uint4 ldY;                                       // Y's AX(t) staged during s1 of each t
    if (tid >= 64 && tid < 128)
        ldY = *(const uint4*)(AXh + ((size_t)0*NPAD + n0 + tid)*8);

    // hoisted biases, prescaled for exp2 activations (shared by both strips)
    float bz_r[2], br_r[2], bh_r[2];
    #pragma unroll
    for (int j = 0; j < 2; j++){
        int col = wc + j*16 + lr;
        bz_r[j] = -LOG2E  * biasg[col];
        br_r[j] = -LOG2E  * biasg[256 + col];
        bh_r[j] =  LOG2E2 * biasg[512 + col];
    }

    h2 accX[16], hrX[16], accY[16], hrY[16], zX[16], zY[16], hrrX[16], hrrY[16];
    h2 z2 = {(_Float16)0.f, (_Float16)0.f};
    #pragma unroll
    for (int k = 0; k < 16; k++){
        accX[k] = z2; hrX[k] = z2; accY[k] = z2; hrY[k] = z2;
    }

    const f4 fz = {0.f, 0.f, 0.f, 0.f};
    __syncthreads();

    for (int t = 0; t < T_P; t++){
        const float pt = probs[t];
        const int last = (t == T_P - 1);
        uint4 ldX;
        if (tid < 64 && !last)
            ldX = *(const uint4*)(AXh + ((size_t)(t+1)*NPAD + n0 + tid)*8);

        // ---- s1: X dual-GEMM (Z,R) on sX  ||  Y writes H'(t-1) + AX(t) into sY ----
        f4 gz[8], gr[8];
        #pragma unroll
        for (int k = 0; k < 8; k++){ gz[k] = fz; gr[k] = fz; }
        gemm_pass2(sX, B1t, wc, 256 + wc, lr, lq, gz, gr);
        epi_zr(gz, gr, hrX, zX, hrrX, bz_r, br_r);
        write_h16(sY, hrY, lq, lr, wc);              // t=0: writes zeros over zeros (ok)
        if (tid >= 64 && tid < 128){
            *(uint4*)(&sY[(tid-64)*LDW]) = ldY;
            if (!last)
                ldY = *(const uint4*)(AXh + ((size_t)(t+1)*NPAD + n0 + tid)*8);
        }
        __syncthreads();

        // ---- s2: X writes H*R into sX  ||  Y dual-GEMM (Z,R) on sY ----
        write_h16(sX, hrrX, lq, lr, wc);
        #pragma unroll
        for (int k = 0; k < 8; k++){ gz[k] = fz; gr[k] = fz; }
        gemm_pass2(sY, B1t, wc, 256 + wc, lr, lq, gz, gr);
        epi_zr(gz, gr, hrY, zY, hrrY, bz_r, br_r);
        __syncthreads();

        // ---- s3: X H~-GEMM on sX + in-register GRU update  ||  Y writes H*R ----
        {
            f4 g[8];
            #pragma unroll
            for (int k = 0; k < 8; k++) g[k] = fz;
            gemm_pass(sX, B2t, wc, lr, lq, g);
            epi_upd(g, zX, hrX, accX, bh_r, pt);
        }
        write_h16(sY, hrrY, lq, lr, wc);
        __syncthreads();

        // ---- s4: X writes H'(t) (or relu(acc)) + AX(t+1)  ||  Y H~-GEMM + update ----
        if (last) write_relu16(sX, accX, lq, lr, wc);
        else      write_h16(sX, hrX, lq, lr, wc);
        if (!last && tid < 64)
            *(uint4*)(&sX[tid*LDW]) = ldX;
        {
            f4 g[8];
            #pragma unroll
            for (int k = 0; k < 8; k++) g[k] = fz;
            gemm_pass(sY, B2t, wc, lr, lq, g);
            epi_upd(g, zY, hrY, accY, bh_r, pt);
        }
        __syncthreads();
    }

    // ---- MLP, strips interleaved; stale AXt cols nulled by zero rows in W*t ----
    f4 gX[8], gY[8];
    float blvP[2] = {0.f, 0.f};
    #pragma unroll
    for (int l = 0; l < 3; l++){
        const _Float16* Wt = (l == 0) ? W1t : (l == 1) ? W2t : W3t;
        const float*    bl = (l == 0) ? b1  : (l == 1) ? b2  : b3;
        float blv[2];
        #pragma unroll
        for (int j = 0; j < 2; j++) blv[j] = bl[wc + j*16 + lr];
        // u1: X gemm layer l || Y write previous result (l==0: relu(accY))
        #pragma unroll
        for (int k = 0; k < 8; k++) gX[k] = fz;
        gemm_pass(sX, Wt, wc, lr, lq, gX);
        if (l == 0) write_relu16(sY, accY, lq, lr, wc);
        else        write_relu_g(sY, gY, blvP, lq, lr, wc);
        __syncthreads();
        // u2: X write relu(gX+b) || Y gemm layer l
        write_relu_g(sX, gX, blv, lq, lr, wc);
        #pragma unroll
        for (int k = 0; k < 8; k++) gY[k] = fz;
        gemm_pass(sY, Wt, wc, lr, lq, gY);
        __syncthreads();
        blvP[0] = blv[0]; blvP[1] = blv[1];
    }
    // u3: Y write layer-2 result
    write_relu_g(sY, gY, blvP, lq, lr, wc);
    __syncthreads();
    // u4: heads (wave0 -> X rows, wave1 -> Y rows; lr/lq patterns are wave-local)
    if (wave == 0)      head_out(sX, WoT, bo, dout, n0,      lr, lq);
    else if (wave == 1) head_out(sY, WoT, bo, dout, n0 + 64, lr, lq);
}

extern "C" void kernel_launch(void* const* d_in, const int* in_sizes, int n_in,
                              void* d_out, int out_size, void* d_ws, size_t ws_size,
                              hipStream_t stream){
    const float* x   = (const float*)d_in[0];
    const int*   ei  = (const int*)  d_in[1];
    const float* ew  = (const float*)d_in[2];
    const float* Wz  = (const float*)d_in[3];  const float* bz  = (const float*)d_in[4];
    const float* Wlz = (const float*)d_in[5];  const float* blz = (const float*)d_in[6];
    const float* Wr  = (const float*)d_in[7];  const float* br  = (const float*)d_in[8];
    const float* Wlr = (const float*)d_in[9];  const float* blr = (const float*)d_in[10];
    const float* Wh  = (const float*)d_in[11]; const float* bh  = (const float*)d_in[12];
    const float* Wlh = (const float*)d_in[13]; const float* blh = (const float*)d_in[14];
    const float* att = (const float*)d_in[15];
    const float* W1  = (const float*)d_in[16]; const float* b1  = (const float*)d_in[17];
    const float* W2  = (const float*)d_in[18]; const float* b2  = (const float*)d_in[19];
    const float* W3  = (const float*)d_in[20]; const float* b3  = (const float*)d_in[21];
    const float* Wo  = (const float*)d_in[22]; const float* bo  = (const float*)d_in[23];
    float* dout = (float*)d_out;

    char* ws = (char*)d_ws; size_t off = 0;
    auto alloc = [&](size_t bytes)->char*{ char* p = ws + off; off += (bytes + 255) & ~(size_t)255; return p; };
    _Float16* AXh   = (_Float16*)alloc((size_t)T_P*NPAD*8*2);   // 28.8M
    float*    deg   = (float*)alloc((size_t)N_NODES*4);
    float*    dinv  = (float*)alloc((size_t)N_NODES*4);
    int*      cnt   = (int*)  alloc((size_t)N_NODES*4);
    int*      rowp  = (int*)  alloc(((size_t)N_NODES + 1)*4);
    int*      ccur  = (int*)  alloc((size_t)N_NODES*4);
    int*      csrc  = (int*)  alloc((size_t)N_EDGES*4);
    float*    cnrm  = (float*)alloc((size_t)N_EDGES*4);
    int*      part  = (int*)  alloc((size_t)NB_SCAN*4);
    int*      pbase = (int*)  alloc((size_t)NB_SCAN*4);
    float*    wprime= (float*)alloc((size_t)3*8*U*4);
    float*    biasg = (float*)alloc((size_t)3*U*4);
    _Float16* B1t   = (_Float16*)alloc((size_t)512*KP*2);
    _Float16* B2t   = (_Float16*)alloc((size_t)256*KP*2);
    _Float16* W1t   = (_Float16*)alloc((size_t)U*KP*2);
    _Float16* W2t   = (_Float16*)alloc((size_t)U*KP*2);
    _Float16* W3t   = (_Float16*)alloc((size_t)U*KP*2);
    _Float16* WoT   = (_Float16*)alloc((size_t)64*KP*2);
    float*    probs = (float*)alloc((size_t)T_P*4);

    hipMemsetAsync(AXh, 0, (size_t)T_P*NPAD*8*2, stream);   // pad-node rows stay zero
    hipMemsetAsync(cnt, 0, (size_t)N_NODES*4, stream);

    k_probs<<<1, 64, 0, stream>>>(att, probs);
    k_wprime<<<(3*9*256 + 255)/256, 256, 0, stream>>>(Wz,bz,Wlz,blz, Wr,br,Wlr,blr, Wh,bh,Wlh,blh, wprime, biasg);
    k_fill_gates<<<(768*KP + 255)/256, 256, 0, stream>>>(wprime, Wlz, Wlr, Wlh, B1t, B2t);
    k_fill_mlp<<<(3*U*KP + 64*KP + 255)/256, 256, 0, stream>>>(W1, W2, W3, Wo, W1t, W2t, W3t, WoT);

    k_init_deg<<<(N_NODES + 255)/256, 256, 0, stream>>>(deg);
    k_deg<<<(N_EDGES + 255)/256, 256, 0, stream>>>(ei, ew, deg);
    k_dinv<<<(N_NODES + 255)/256, 256, 0, stream>>>(deg, dinv);
    k_count<<<(N_EDGES + 255)/256, 256, 0, stream>>>(ei, cnt);
    k_partial<<<NB_SCAN, 256, 0, stream>>>(cnt, part);
    k_scan_part<<<1, 512, 0, stream>>>(part, pbase);
    k_emit<<<NB_SCAN, 256, 0, stream>>>(cnt, pbase, rowp, ccur);
    k_scatter<<<(N_EDGES + 255)/256, 256, 0, stream>>>(ei, ew, dinv, ccur, csrc, cnrm);
    k_gather_nf<<<(N_NODES*8 + 255)/256, 256, 0, stream>>>(x, dinv, rowp, csrc, cnrm, AXh);

    k_fused<<<NPAD/128, 512, 0, stream>>>(AXh, B1t, B2t, biasg, W1t, W2t, W3t, WoT,
                                          b1, b2, b3, bo, probs, dout);
}

// Round 8
// 2174.621 us; speedup vs baseline: 1.3862x; 1.3862x over previous
//
#include <hip/hip_runtime.h>

typedef _Float16 h8 __attribute__((ext_vector_type(8)));
typedef _Float16 h2 __attribute__((ext_vector_type(2)));
typedef float f4 __attribute__((ext_vector_type(4)));

#define N_NODES 100000
#define NPAD    100096   // 1564*64
#define N_EDGES 1600000
#define T_P  18
#define U    256
#define KP   288         // padded K: 8 AXt + 256 H + 24 zero
#define LDW  296         // LDS row stride in halfs (148 words = 20 mod 32 -> 2-way alias only, free)
#define NB_SCAN 391      // ceil(N_NODES/256)

#define LOG2E  1.44269504f
#define LOG2E2 2.88539008f

// ---------------- degree / norm / CSR ----------------
__global__ void k_init_deg(float* deg){
    int i = blockIdx.x*256 + threadIdx.x;
    if (i < N_NODES) deg[i] = 1.0f;
}
__global__ void k_deg(const int* __restrict__ ei, const float* __restrict__ w, float* deg){
    int e = blockIdx.x*256 + threadIdx.x;
    if (e < N_EDGES) atomicAdd(&deg[ei[N_EDGES + e]], w[e]);
}
__global__ void k_dinv(const float* deg, float* dinv){
    int i = blockIdx.x*256 + threadIdx.x;
    if (i < N_NODES) dinv[i] = rsqrtf(deg[i]);
}
__global__ void k_count(const int* __restrict__ ei, int* cnt){
    int e = blockIdx.x*256 + threadIdx.x;
    if (e < N_EDGES) atomicAdd(&cnt[ei[N_EDGES + e]], 1);
}
// parallel scan: per-256-chunk sums -> scan of partials -> emit offsets
__global__ void k_partial(const int* __restrict__ cnt, int* part){
    __shared__ int red[256];
    int b = blockIdx.x, i = b*256 + threadIdx.x;
    red[threadIdx.x] = (i < N_NODES) ? cnt[i] : 0;
    __syncthreads();
    for (int d = 128; d > 0; d >>= 1){
        if (threadIdx.x < d) red[threadIdx.x] += red[threadIdx.x + d];
        __syncthreads();
    }
    if (threadIdx.x == 0) part[b] = red[0];
}
__global__ void k_scan_part(const int* __restrict__ part, int* pbase){
    __shared__ int s[512];
    int tid = threadIdx.x;
    int v = (tid < NB_SCAN) ? part[tid] : 0;
    s[tid] = v; __syncthreads();
    for (int d = 1; d < 512; d <<= 1){
        int t2 = (tid >= d) ? s[tid - d] : 0;
        __syncthreads();
        s[tid] += t2;
        __syncthreads();
    }
    if (tid < NB_SCAN) pbase[tid] = s[tid] - v;   // exclusive
}
__global__ void k_emit(const int* __restrict__ cnt, const int* __restrict__ pbase,
                       int* rowp, int* ccur){
    __shared__ int s[256];
    int b = blockIdx.x, tid = threadIdx.x, i = b*256 + tid;
    int v = (i < N_NODES) ? cnt[i] : 0;
    s[tid] = v; __syncthreads();
    for (int d = 1; d < 256; d <<= 1){
        int t2 = (tid >= d) ? s[tid - d] : 0;
        __syncthreads();
        s[tid] += t2;
        __syncthreads();
    }
    int excl = s[tid] - v + pbase[b];
    if (i < N_NODES){
        rowp[i] = excl; ccur[i] = excl;
        if (i == N_NODES - 1) rowp[N_NODES] = excl + v;
    }
}
__global__ void k_scatter(const int* __restrict__ ei, const float* __restrict__ w,
                          const float* __restrict__ dinv, int* ccur,
                          int* __restrict__ csrc, float* __restrict__ cnrm){
    int e = blockIdx.x*256 + threadIdx.x;
    if (e >= N_EDGES) return;
    int s = ei[e], d = ei[N_EDGES + e];
    int pos = atomicAdd(&ccur[d], 1);
    csrc[pos] = s;
    cnrm[pos] = dinv[s] * w[e] * dinv[d];
}
// one thread per (node, feature): 18 time-accumulators, fp16 out
__global__ void k_gather_nf(const float* __restrict__ x, const float* __restrict__ dinv,
                            const int* __restrict__ rowp, const int* __restrict__ csrc,
                            const float* __restrict__ cnrm, _Float16* __restrict__ AXh){
    int idx = blockIdx.x*256 + threadIdx.x;
    if (idx >= N_NODES*8) return;
    int n = idx >> 3, f = idx & 7;
    float dv = dinv[n];
    float w0 = dv * dv;
    const float* xb = x + (size_t)n*144 + f*18;
    float s[T_P];
    #pragma unroll
    for (int t = 0; t < T_P; t++) s[t] = w0 * xb[t];
    int p1 = rowp[n+1];
    for (int p = rowp[n]; p < p1; p++){
        float w = cnrm[p];
        const float* xs = x + (size_t)csrc[p]*144 + f*18;
        #pragma unroll
        for (int t = 0; t < T_P; t++) s[t] += w * xs[t];
    }
    #pragma unroll
    for (int t = 0; t < T_P; t++)
        AXh[((size_t)t*NPAD + n)*8 + f] = (_Float16)s[t];
}

// ---------------- weight prep ----------------
__global__ void k_probs(const float* att, float* probs){
    if (threadIdx.x == 0 && blockIdx.x == 0){
        float mx = -1e30f;
        for (int t = 0; t < T_P; t++) mx = fmaxf(mx, att[t]);
        float e[T_P], s = 0.f;
        for (int t = 0; t < T_P; t++){ e[t] = __expf(att[t] - mx); s += e[t]; }
        for (int t = 0; t < T_P; t++) probs[t] = e[t] / s;
    }
}
__global__ void k_wprime(const float* Wz, const float* bz, const float* Wlz, const float* blz,
                         const float* Wr, const float* br, const float* Wlr, const float* blr,
                         const float* Wh, const float* bh, const float* Wlh, const float* blh,
                         float* wprime, float* biasg){
    int idx = blockIdx.x*256 + threadIdx.x;
    if (idx >= 3*9*256) return;
    int g = idx / (9*256); int rem = idx - g*9*256;
    int row = rem / 256;   int u = rem - row*256;
    const float* W  = g==0 ? Wz  : (g==1 ? Wr  : Wh);
    const float* Wl = g==0 ? Wlz : (g==1 ? Wlr : Wlh);
    const float* bb = g==0 ? bz  : (g==1 ? br  : bh);
    const float* bl = g==0 ? blz : (g==1 ? blr : blh);
    float s = 0.f;
    if (row < 8){
        for (int c = 0; c < U; c++) s += W[row*U + c] * Wl[c*U + u];
        wprime[(g*8 + row)*U + u] = s;
    } else {
        for (int c = 0; c < U; c++) s += bb[c] * Wl[c*U + u];
        biasg[g*U + u] = s + bl[u];
    }
}
// B1t [512][288] (Z|R), B2t [256][288] (H~), n-major fp16, K-padded with 0
__global__ void k_fill_gates(const float* __restrict__ wprime, const float* __restrict__ Wlz,
                             const float* __restrict__ Wlr, const float* __restrict__ Wlh,
                             _Float16* __restrict__ B1t, _Float16* __restrict__ B2t){
    int idx = blockIdx.x*256 + threadIdx.x;
    if (idx >= 768*KP) return;
    int n = idx / KP, k = idx - n*KP;
    int g = (n < 256) ? 0 : ((n < 512) ? 1 : 2);
    int u = n & 255;
    const float* Wl = g==0 ? Wlz : (g==1 ? Wlr : Wlh);
    float v;
    if (k < 8)        v = wprime[(g*8 + k)*U + u];
    else if (k < 264) v = Wl[(256 + (k - 8))*U + u];
    else              v = 0.f;
    if (n < 512) B1t[(size_t)n*KP + k] = (_Float16)v;
    else         B2t[(size_t)(n - 512)*KP + k] = (_Float16)v;
}
// MLP weights in same padded layout: rows k<8 and k>=264 are zero, k in [8,264) = W[k-8][n]
__global__ void k_fill_mlp(const float* __restrict__ W1, const float* __restrict__ W2,
                           const float* __restrict__ W3, const float* __restrict__ Wo,
                           _Float16* W1t, _Float16* W2t, _Float16* W3t, _Float16* WoT){
    int idx = blockIdx.x*256 + threadIdx.x;
    if (idx >= 3*U*KP + 64*KP) return;
    if (idx < 3*U*KP){
        int l = idx / (U*KP); int rem = idx - l*U*KP;
        int n = rem / KP, k = rem - n*KP;
        const float* W = l==0 ? W1 : (l==1 ? W2 : W3);
        _Float16*   Wt = l==0 ? W1t : (l==1 ? W2t : W3t);
        Wt[(size_t)n*KP + k] = (k >= 8 && k < 264) ? (_Float16)W[(size_t)(k-8)*U + n] : (_Float16)0.f;
    } else {
        int rem = idx - 3*U*KP;
        int n = rem / KP, k = rem - n*KP;
        WoT[(size_t)n*KP + k] = (n < T_P && k >= 8 && k < 264) ? (_Float16)Wo[(size_t)(k-8)*T_P + n] : (_Float16)0.f;
    }
}

// ---------------- fused recurrence + MLP ----------------
// R8 wave tile = 64 rows x 16 cols: g[4] (4 row-frags x 1 col-frag)
__device__ __forceinline__ void gemm_pass(const _Float16* sbuf, const _Float16* __restrict__ Bg,
                                          int brow, int lr, int lq, f4* g){
    for (int kt = 0; kt < 9; kt++){
        h8 af[4], bf;
        #pragma unroll
        for (int i = 0; i < 4; i++)
            af[i] = *(const h8*)(sbuf + (i*16 + lr)*LDW + kt*32 + lq*8);
        bf = *(const h8*)(Bg + (size_t)(brow + lr)*KP + kt*32 + lq*8);
        #pragma unroll
        for (int i = 0; i < 4; i++)
            g[i] = __builtin_amdgcn_mfma_f32_16x16x32_f16(af[i], bf, g[i], 0, 0, 0);
    }
}

// R1: exp2/rcp epilogues, H in regs, AX reg-prefetch -> 1804us @ 64x32 tile, 512 thr.
// R2/R3/R5: waves_per_eu attr levers DEAD. R4 (merged Z+R): 2025us, reg pressure.
// R6/R7 (two strips): 2610us, spill signature (WRITE 0.5->2.1 GB) — state doubled.
// R8 occupancy model (consistent with ALL rounds): reported VGPR=128 is arch-only;
//   +AGPR accumulators => ~160 unified/wave => 8 waves/CU bucket (m69 steps at
//   64/128/256) => 20.7% forever. Fix by SHRINKING the wave tile to 64x16 with
//   1024-thread blocks (16 waves x 16 cols): per-wave state ~95 unified
//   (acc/hr/htr=24, g=16, frags ~20, addr ~20). __launch_bounds__(1024) forces the
//   allocator to fit 4 waves/SIMD (128 budget) -- the one occupancy lever that
//   cannot be ignored -- and demand is well under it, so no spills. Schedule,
//   barriers, staging, LDS layout identical to the proven R1 kernel.
__global__ __launch_bounds__(1024)
void k_fused(const _Float16* __restrict__ AXh,
             const _Float16* __restrict__ B1t, const _Float16* __restrict__ B2t,
             const float* __restrict__ biasg,
             const _Float16* __restrict__ W1t, const _Float16* __restrict__ W2t,
             const _Float16* __restrict__ W3t, const _Float16* __restrict__ WoT,
             const float* __restrict__ b1, const float* __restrict__ b2,
             const float* __restrict__ b3, const float* __restrict__ bo,
             const float* __restrict__ probs, float* __restrict__ dout){
    __shared__ __align__(16) _Float16 sA[64*LDW];   // [AXt | H    | pad]
    __shared__ __align__(16) _Float16 sB[64*LDW];   // [AXt | H*R  | pad]
    const int tid  = threadIdx.x;
    const int wave = tid >> 6, lane = tid & 63;
    const int lr = lane & 15, lq = lane >> 4;
    const int wc = wave * 16;                        // this wave's 16 output cols
    const int n0 = blockIdx.x * 64;

    {   // zero both buffers (H cols start 0, pad cols stay 0)
        uint* w0 = (uint*)sA; uint* w1 = (uint*)sB;
        for (int i = tid; i < 64*LDW/2; i += 1024){ w0[i] = 0u; w1[i] = 0u; }
    }
    __syncthreads();
    if (tid < 64)
        *(uint4*)(&sA[tid*LDW]) = *(const uint4*)(AXh + ((size_t)0*NPAD + n0 + tid)*8);
    else if (tid < 128)
        *(uint4*)(&sB[(tid-64)*LDW]) = *(const uint4*)(AXh + ((size_t)0*NPAD + n0 + (tid-64))*8);

    // hoist biases (constant across t), prescaled for exp2-based activations: 3 VGPRs
    const int bcol = wc + lr;
    const float bz_r = -LOG2E  * biasg[bcol];
    const float br_r = -LOG2E  * biasg[256 + bcol];
    const float bh_r =  LOG2E2 * biasg[512 + bcol];

    h2 acc[8], hr[8], htr[8];
    h2 z2 = {(_Float16)0.f, (_Float16)0.f};
    #pragma unroll
    for (int k = 0; k < 8; k++){ acc[k] = z2; hr[k] = z2; }

    f4 g[4];
    const f4 fz = {0.f, 0.f, 0.f, 0.f};
    __syncthreads();

    for (int t = 0; t < T_P; t++){
        const float pt = probs[t];
        const int last = (t == T_P - 1);
        // prefetch AXt+1 into regs now; LDS write happens after the 2nd barrier
        uint4 nx;
        if (!last){
            if (tid < 64)
                nx = *(const uint4*)(AXh + ((size_t)(t+1)*NPAD + n0 + tid)*8);
            else if (tid < 128)
                nx = *(const uint4*)(AXh + ((size_t)(t+1)*NPAD + n0 + (tid-64))*8);
        }
        // ---- GEMM-R (reads sA) ----
        #pragma unroll
        for (int k = 0; k < 4; k++) g[k] = fz;
        gemm_pass(sA, B1t, 256 + wc, lr, lq, g);
        // epi-R: sB.H*R = h * sigmoid(.)  (h carried in hr regs)
        #pragma unroll
        for (int i = 0; i < 4; i++)
            #pragma unroll
            for (int r = 0; r < 4; r++){
                int v = i*4 + r;
                int row = i*16 + lq*4 + r;
                float rr = __builtin_amdgcn_rcpf(
                    1.f + __builtin_amdgcn_exp2f(fmaf(g[i][r], -LOG2E, br_r)));
                sB[row*LDW + 8 + bcol] = (_Float16)((float)hr[v>>1][v&1] * rr);
            }
        __syncthreads();                       // sB (H*R) complete
        // ---- GEMM-H~ (reads sB) ----
        #pragma unroll
        for (int k = 0; k < 4; k++) g[k] = fz;
        gemm_pass(sB, B2t, wc, lr, lq, g);
        // epi-H~: ht -> regs (no LDS)
        #pragma unroll
        for (int i = 0; i < 4; i++)
            #pragma unroll
            for (int r = 0; r < 4; r++){
                int v = i*4 + r;
                float e2 = __builtin_amdgcn_exp2f(fmaf(g[i][r], LOG2E2, bh_r));
                htr[v>>1][v&1] = (_Float16)fmaf(-2.f, __builtin_amdgcn_rcpf(e2 + 1.f), 1.f);
            }
        // ---- GEMM-Z (reads sA only; no barrier needed since last one) ----
        #pragma unroll
        for (int k = 0; k < 4; k++) g[k] = fz;
        gemm_pass(sA, B1t, wc, lr, lq, g);
        __syncthreads();                       // all GEMM-Z/H~ reads done
        // epi-Z: GRU update in place + attention accumulate (+ final relu fuse)
        #pragma unroll
        for (int i = 0; i < 4; i++)
            #pragma unroll
            for (int r = 0; r < 4; r++){
                int v = i*4 + r;
                int row = i*16 + lq*4 + r;
                float z = __builtin_amdgcn_rcpf(
                    1.f + __builtin_amdgcn_exp2f(fmaf(g[i][r], -LOG2E, bz_r)));
                float h  = (float)hr[v>>1][v&1];
                float ht = (float)htr[v>>1][v&1];
                float hn = fmaf(z, h - ht, ht);
                float a  = fmaf(pt, hn, (float)acc[v>>1][v&1]);
                acc[v>>1][v&1] = (_Float16)a;
                hr[v>>1][v&1]  = (_Float16)hn;
                sA[row*LDW + 8 + bcol] = (_Float16)(last ? fmaxf(a, 0.f) : hn);
            }
        if (!last){
            if (tid < 64)
                *(uint4*)(&sA[tid*LDW]) = nx;
            else if (tid < 128)
                *(uint4*)(&sB[(tid-64)*LDW]) = nx;
        }
        __syncthreads();                       // H' (or relu(acc)), AXt+1 visible
    }

    // ---- MLP in place on sA; stale AXt cols nulled by zero rows in W*t ----
    #pragma unroll
    for (int l = 0; l < 3; l++){
        const _Float16* Wt = (l == 0) ? W1t : (l == 1) ? W2t : W3t;
        const float*    bl = (l == 0) ? b1  : (l == 1) ? b2  : b3;
        const float blv = bl[bcol];
        #pragma unroll
        for (int k = 0; k < 4; k++) g[k] = fz;
        gemm_pass(sA, Wt, wc, lr, lq, g);
        __syncthreads();                       // all reads done before in-place write
        #pragma unroll
        for (int i = 0; i < 4; i++)
            #pragma unroll
            for (int r = 0; r < 4; r++){
                int row = i*16 + lq*4 + r;
                sA[row*LDW + 8 + bcol] = (_Float16)fmaxf(g[i][r] + blv, 0.f);
            }
        __syncthreads();
    }
    // ---- head: 64x18, waves 0 and 1 (cols 0-15 and 16-17; WoT rows >=T_P are 0) ----
    if (wave < 2){
        #pragma unroll
        for (int k = 0; k < 4; k++) g[k] = fz;
        gemm_pass(sA, WoT, wave*16, lr, lq, g);
        #pragma unroll
        for (int i = 0; i < 4; i++)
            #pragma unroll
            for (int r = 0; r < 4; r++){
                int row = i*16 + lq*4 + r;
                int col = wave*16 + lr;
                int gm = n0 + row;
                if (col < T_P && gm < N_NODES)
                    dout[(size_t)gm*T_P + col] = g[i][r] + bo[col];
            }
    }
}

extern "C" void kernel_launch(void* const* d_in, const int* in_sizes, int n_in,
                              void* d_out, int out_size, void* d_ws, size_t ws_size,
                              hipStream_t stream){
    const float* x   = (const float*)d_in[0];
    const int*   ei  = (const int*)  d_in[1];
    const float* ew  = (const float*)d_in[2];
    const float* Wz  = (const float*)d_in[3];  const float* bz  = (const float*)d_in[4];
    const float* Wlz = (const float*)d_in[5];  const float* blz = (const float*)d_in[6];
    const float* Wr  = (const float*)d_in[7];  const float* br  = (const float*)d_in[8];
    const float* Wlr = (const float*)d_in[9];  const float* blr = (const float*)d_in[10];
    const float* Wh  = (const float*)d_in[11]; const float* bh  = (const float*)d_in[12];
    const float* Wlh = (const float*)d_in[13]; const float* blh = (const float*)d_in[14];
    const float* att = (const float*)d_in[15];
    const float* W1  = (const float*)d_in[16]; const float* b1  = (const float*)d_in[17];
    const float* W2  = (const float*)d_in[18]; const float* b2  = (const float*)d_in[19];
    const float* W3  = (const float*)d_in[20]; const float* b3  = (const float*)d_in[21];
    const float* Wo  = (const float*)d_in[22]; const float* bo  = (const float*)d_in[23];
    float* dout = (float*)d_out;

    char* ws = (char*)d_ws; size_t off = 0;
    auto alloc = [&](size_t bytes)->char*{ char* p = ws + off; off += (bytes + 255) & ~(size_t)255; return p; };
    _Float16* AXh   = (_Float16*)alloc((size_t)T_P*NPAD*8*2);   // 28.8M
    float*    deg   = (float*)alloc((size_t)N_NODES*4);
    float*    dinv  = (float*)alloc((size_t)N_NODES*4);
    int*      cnt   = (int*)  alloc((size_t)N_NODES*4);
    int*      rowp  = (int*)  alloc(((size_t)N_NODES + 1)*4);
    int*      ccur  = (int*)  alloc((size_t)N_NODES*4);
    int*      csrc  = (int*)  alloc((size_t)N_EDGES*4);
    float*    cnrm  = (float*)alloc((size_t)N_EDGES*4);
    int*      part  = (int*)  alloc((size_t)NB_SCAN*4);
    int*      pbase = (int*)  alloc((size_t)NB_SCAN*4);
    float*    wprime= (float*)alloc((size_t)3*8*U*4);
    float*    biasg = (float*)alloc((size_t)3*U*4);
    _Float16* B1t   = (_Float16*)alloc((size_t)512*KP*2);
    _Float16* B2t   = (_Float16*)alloc((size_t)256*KP*2);
    _Float16* W1t   = (_Float16*)alloc((size_t)U*KP*2);
    _Float16* W2t   = (_Float16*)alloc((size_t)U*KP*2);
    _Float16* W3t   = (_Float16*)alloc((size_t)U*KP*2);
    _Float16* WoT   = (_Float16*)alloc((size_t)64*KP*2);
    float*    probs = (float*)alloc((size_t)T_P*4);

    hipMemsetAsync(AXh, 0, (size_t)T_P*NPAD*8*2, stream);   // pad-node rows stay zero
    hipMemsetAsync(cnt, 0, (size_t)N_NODES*4, stream);

    k_probs<<<1, 64, 0, stream>>>(att, probs);
    k_wprime<<<(3*9*256 + 255)/256, 256, 0, stream>>>(Wz,bz,Wlz,blz, Wr,br,Wlr,blr, Wh,bh,Wlh,blh, wprime, biasg);
    k_fill_gates<<<(768*KP + 255)/256, 256, 0, stream>>>(wprime, Wlz, Wlr, Wlh, B1t, B2t);
    k_fill_mlp<<<(3*U*KP + 64*KP + 255)/256, 256, 0, stream>>>(W1, W2, W3, Wo, W1t, W2t, W3t, WoT);

    k_init_deg<<<(N_NODES + 255)/256, 256, 0, stream>>>(deg);
    k_deg<<<(N_EDGES + 255)/256, 256, 0, stream>>>(ei, ew, deg);
    k_dinv<<<(N_NODES + 255)/256, 256, 0, stream>>>(deg, dinv);
    k_count<<<(N_EDGES + 255)/256, 256, 0, stream>>>(ei, cnt);
    k_partial<<<NB_SCAN, 256, 0, stream>>>(cnt, part);
    k_scan_part<<<1, 512, 0, stream>>>(part, pbase);
    k_emit<<<NB_SCAN, 256, 0, stream>>>(cnt, pbase, rowp, ccur);
    k_scatter<<<(N_EDGES + 255)/256, 256, 0, stream>>>(ei, ew, dinv, ccur, csrc, cnrm);
    k_gather_nf<<<(N_NODES*8 + 255)/256, 256, 0, stream>>>(x, dinv, rowp, csrc, cnrm, AXh);

    k_fused<<<NPAD/64, 1024, 0, stream>>>(AXh, B1t, B2t, biasg, W1t, W2t, W3t, WoT,
                                          b1, b2, b3, bo, probs, dout);
}